// Round 12
// baseline (1154.250 us; speedup 1.0000x reference)
//
#include <hip/hip_runtime.h>
#include <hip/hip_bf16.h>

// WMSA round 8: LDS diet (26 KB -> 6 blocks/CU) + register-resident stack.
//  - x -> A-frags directly from global (no s_win, no stage barrier)
//  - PV with swapped MFMA args -> O^T lives in registers (pk2, bf16 pairs)
//  - out-proj B-frags via 24-shfl cross-lane redistribution of pk2
//  - convergence barrier before stores (restores full-line write combining)
// One block (256 thr = 4 waves) per window; wave wv owns tokens [16wv,16wv+16).

#define CH    96
#define MMTOK 49
#define HWD   224
#define PLANE (HWD * HWD)

typedef __attribute__((ext_vector_type(8))) __bf16 bfrag;
typedef __attribute__((ext_vector_type(4))) float  f4;
#define MFMA(a,b,c) __builtin_amdgcn_mfma_f32_16x16x32_bf16(a,b,c,0,0,0)

// ws layout (bf16 element offsets): qkv_w [288][96], out_w [96][96]
#define WS_OW  27648
#define WS_TOT 36864

// LDS pitches (bf16 elems); strides keep b128 reads <=2-way bank conflicts
#define PW_K 40    // s_k [64][32]
#define PW_Q 40    // per-wave Q strip [16][32]
#define PW_V 72    // s_vT [32][64]
#define PW_P 72    // per-wave P strip [16][64]

extern "C" __global__ void __launch_bounds__(256)
cvt_weights(const float* __restrict__ qw, const float* __restrict__ ow,
            __hip_bfloat16* __restrict__ ws)
{
    int i = blockIdx.x * 256 + threadIdx.x;
    if (i >= WS_TOT) return;
    ws[i] = __float2bfloat16(i < WS_OW ? qw[i] : ow[i - WS_OW]);
}

__device__ __forceinline__ unsigned packbf2(float lo, float hi) {
    union { __hip_bfloat16 h[2]; unsigned u; } p;
    p.h[0] = __float2bfloat16(lo);
    p.h[1] = __float2bfloat16(hi);
    return p.u;
}

extern "C" __global__ void __launch_bounds__(256, 6)
wmsa_mfma(const float* __restrict__ x,
          const __hip_bfloat16* __restrict__ ws,
          const float* __restrict__ qkvb,   // f32 [288]
          const float* __restrict__ bt,     // f32 [507]
          const float* __restrict__ outb,   // f32 [96]
          float* __restrict__ out)
{
    __shared__ __align__(16) __hip_bfloat16 s_k [64 * PW_K];     // K [tok][d]
    __shared__ __align__(16) __hip_bfloat16 s_vT[32 * PW_V];     // V^T [d][tok]
    __shared__ __align__(16) __hip_bfloat16 s_q [4][16 * PW_Q];  // per-wave Q strip
    __shared__ __align__(16) __hip_bfloat16 s_P [4][16 * PW_P];  // per-wave P strip
    __shared__ float s_bias[507];

    const int tid  = threadIdx.x;
    // XCD-bijective swizzle (gridDim.x = 16384, %8==0)
    const int cpx  = gridDim.x >> 3;
    const int wid  = (blockIdx.x & 7) * cpx + (blockIdx.x >> 3);
    const int b    = wid >> 10;
    const int w    = wid & 1023;
    const int h0   = (w >> 5) * 7;
    const int w0   = (w & 31) * 7;
    const int lane = tid & 63;
    const int wv   = tid >> 6;
    const int lr   = lane & 15;
    const int lg   = lane >> 4;

    const __hip_bfloat16* QW = ws;
    const __hip_bfloat16* OW = ws + WS_OW;

    // ---- stage bias table ----
    for (int i = tid; i < 507; i += 256) s_bias[i] = bt[i];

    // ---- x -> A-frags directly (token t = wv*16+lr, channels k3*32+lg*8+j) ----
    const int t  = wv * 16 + lr;
    const int tt = (t < MMTOK) ? t : 0;
    const int ti = tt / 7, tj = tt - ti * 7;
    const float zm = (t < MMTOK) ? 1.f : 0.f;
    bfrag aq[3];
    {
        const float* xp = x + (size_t)b * CH * PLANE
                            + (size_t)(h0 + ti) * HWD + (w0 + tj);
        float rx[24];
        #pragma unroll
        for (int k3 = 0; k3 < 3; ++k3)
            #pragma unroll
            for (int j = 0; j < 8; ++j)
                rx[k3 * 8 + j] = xp[(size_t)(k3 * 32 + lg * 8 + j) * PLANE];
        #pragma unroll
        for (int k3 = 0; k3 < 3; ++k3) {
            union { __hip_bfloat16 h[8]; bfrag v; } u;
            #pragma unroll
            for (int j = 0; j < 8; ++j)
                u.h[j] = __float2bfloat16(rx[k3 * 8 + j] * zm);
            aq[k3] = u.v;
        }
    }

    // ---- per-lane bias indices: p = wv*16+lr fixed; k = m*16+lg*4+r ----
    const bool pok = (t < MMTOK);
    const int a1p = ((tt / 7) * 13 + (tt % 7)) * 3 + 252;
    int bidx[16];
    #pragma unroll
    for (int m = 0; m < 4; ++m)
        #pragma unroll
        for (int r = 0; r < 4; ++r) {
            int kt = m * 16 + lg * 4 + r;
            int kc = (kt < MMTOK) ? kt : 48;
            bidx[m * 4 + r] = a1p - ((kc / 7) * 13 + (kc % 7)) * 3;
        }

    const float inv_scale = 0.0180421959f;             // sqrt(3)/96
    unsigned pk2[6][2];                                 // O^T bf16 pairs (stack)

    // ==== per-head (unrolled: pk2 must be statically indexed) ====
    #pragma unroll
    for (int ob = 0; ob < 3; ++ob) {
        // --- QKV GEMM chunk ob, register-double-buffered B-frags from L2 ---
        const __hip_bfloat16* QWrow = QW + (ob * 96 + lr) * 96 + lg * 8;
        f4 acc[6];
        #pragma unroll
        for (int n = 0; n < 6; ++n) {
            float bb = qkvb[ob * 96 + n * 16 + lr];
            acc[n] = f4{bb, bb, bb, bb};
        }
        bfrag b0[6], b1[6];
        #pragma unroll
        for (int n = 0; n < 6; ++n) b0[n] = *(const bfrag*)&QWrow[n * 16 * 96 + 0 * 32];
        #pragma unroll
        for (int n = 0; n < 6; ++n) b1[n] = *(const bfrag*)&QWrow[n * 16 * 96 + 1 * 32];
        __builtin_amdgcn_s_setprio(1);
        #pragma unroll
        for (int n = 0; n < 6; ++n) acc[n] = MFMA(aq[0], b0[n], acc[n]);
        __builtin_amdgcn_s_setprio(0);
        #pragma unroll
        for (int n = 0; n < 6; ++n) b0[n] = *(const bfrag*)&QWrow[n * 16 * 96 + 2 * 32];
        __builtin_amdgcn_s_setprio(1);
        #pragma unroll
        for (int n = 0; n < 6; ++n) acc[n] = MFMA(aq[1], b1[n], acc[n]);
        #pragma unroll
        for (int n = 0; n < 6; ++n) acc[n] = MFMA(aq[2], b0[n], acc[n]);
        __builtin_amdgcn_s_setprio(0);

        if (ob) __syncthreads();   // [A] prev head's s_k/s_vT reads complete

        // C-store: n=0,1 -> Q (wave-private) ; n=2,3 -> K ; n=4,5 -> V^T
        #pragma unroll
        for (int n = 0; n < 6; ++n) {
            int part = n >> 1;
            int d = ((n & 1) << 4) + lr;
            #pragma unroll
            for (int r = 0; r < 4; ++r) {
                __hip_bfloat16 hv = __float2bfloat16(acc[n][r]);
                int tk = wv * 16 + lg * 4 + r;
                if (part == 0)      s_q[wv][(lg * 4 + r) * PW_Q + d] = hv;
                else if (part == 1) s_k[tk * PW_K + d] = hv;
                else                s_vT[d * PW_V + tk] = hv;
            }
        }
        __syncthreads();           // [B] K, V visible to all waves

        // --- swapped QK^T: lane holds scores of its own query row p=wv*16+lr ---
        bfrag qf = *(const bfrag*)&s_q[wv][lr * PW_Q + lg * 8];
        f4 sc[4];
        __builtin_amdgcn_s_setprio(1);
        #pragma unroll
        for (int m = 0; m < 4; ++m) {
            bfrag kf = *(const bfrag*)&s_k[(m * 16 + lr) * PW_K + lg * 8];
            f4 z = f4{0.f, 0.f, 0.f, 0.f};
            sc[m] = MFMA(kf, qf, z);
        }
        __builtin_amdgcn_s_setprio(0);

        // --- in-lane softmax (2 shuffles) ---
        float val[16];
        #pragma unroll
        for (int m = 0; m < 4; ++m)
            #pragma unroll
            for (int r = 0; r < 4; ++r)
                val[m * 4 + r] = fmaf(sc[m][r], inv_scale, s_bias[bidx[m * 4 + r] + ob]);
        float mx = fmaxf(fmaxf(fmaxf(val[0], val[1]), fmaxf(val[2], val[3])),
                   fmaxf(fmaxf(fmaxf(val[4], val[5]), fmaxf(val[6], val[7])),
                   fmaxf(fmaxf(fmaxf(val[8], val[9]), fmaxf(val[10], val[11])),
                         fmaxf(fmaxf(val[12], val[13]), fmaxf(val[14], val[15])))));
        mx = fmaxf(mx, __shfl_xor(mx, 16));
        mx = fmaxf(mx, __shfl_xor(mx, 32));
        float sum = 0.f;
        #pragma unroll
        for (int m = 0; m < 4; ++m)
            #pragma unroll
            for (int r = 0; r < 4; ++r) {
                int i = m * 4 + r;
                float e = __expf(val[i] - mx);
                e = (m * 16 + lg * 4 + r < MMTOK) ? e : 0.f;
                val[i] = e;
                sum += e;
            }
        sum += __shfl_xor(sum, 16);
        sum += __shfl_xor(sum, 32);
        const float inv = pok ? (1.0f / sum) : 0.f;

        // P strip (wave-private): lane writes its 16 values, 4x uint2
        #pragma unroll
        for (int m = 0; m < 4; ++m) {
            union { __hip_bfloat16 h[4]; uint2 u; } pk;
            #pragma unroll
            for (int r = 0; r < 4; ++r) pk.h[r] = __float2bfloat16(val[m * 4 + r] * inv);
            *(uint2*)&s_P[wv][lr * PW_P + m * 16 + lg * 4] = pk.u;
        }
        // same-wave RAW on s_P: lgkmcnt ordering, no barrier

        // --- PV, swapped args -> O^T in registers ---
        bfrag pa0 = *(const bfrag*)&s_P[wv][lr * PW_P + 0 * 32 + lg * 8];
        bfrag pa1 = *(const bfrag*)&s_P[wv][lr * PW_P + 1 * 32 + lg * 8];
        __builtin_amdgcn_s_setprio(1);
        #pragma unroll
        for (int nblk = 0; nblk < 2; ++nblk) {
            bfrag vb0 = *(const bfrag*)&s_vT[(nblk * 16 + lr) * PW_V + 0 * 32 + lg * 8];
            bfrag vb1 = *(const bfrag*)&s_vT[(nblk * 16 + lr) * PW_V + 1 * 32 + lg * 8];
            f4 oc = f4{0.f, 0.f, 0.f, 0.f};
            oc = MFMA(vb0, pa0, oc);     // A = V^T, B = P^T  ->  D = O^T
            oc = MFMA(vb1, pa1, oc);
            pk2[ob * 2 + nblk][0] = packbf2(oc[0], oc[1]);
            pk2[ob * 2 + nblk][1] = packbf2(oc[2], oc[3]);
        }
        __builtin_amdgcn_s_setprio(0);
    }

    __syncthreads();   // [F] converge waves: stores land together (write combining)

    // ==== out-proj, swapped: y^T[o][t] = OW x stack^T ====
    f4 yac[6];
    #pragma unroll
    for (int nb = 0; nb < 6; ++nb) {
        float4 bb4 = *(const float4*)&outb[nb * 16 + lg * 4];
        yac[nb] = f4{bb4.x, bb4.y, bb4.z, bb4.w};
    }
    const int sA = lr + 16 * (2 * (lg & 1));
    const bool hi = ((lg >> 1) & 1) != 0;
    #pragma unroll
    for (int kb = 0; kb < 3; ++kb) {
        // redistribute pk2 -> B-frag (stack^T pairs for c = kb*32 + lg*8 + 2u)
        unsigned A00 = __shfl(pk2[2 * kb + 0][0], sA);
        unsigned A01 = __shfl(pk2[2 * kb + 0][1], sA);
        unsigned A10 = __shfl(pk2[2 * kb + 1][0], sA);
        unsigned A11 = __shfl(pk2[2 * kb + 1][1], sA);
        unsigned B00 = __shfl(pk2[2 * kb + 0][0], sA + 16);
        unsigned B01 = __shfl(pk2[2 * kb + 0][1], sA + 16);
        unsigned B10 = __shfl(pk2[2 * kb + 1][0], sA + 16);
        unsigned B11 = __shfl(pk2[2 * kb + 1][1], sA + 16);
        union { unsigned w[4]; bfrag v; } sb;
        sb.w[0] = hi ? A10 : A00;
        sb.w[1] = hi ? A11 : A01;
        sb.w[2] = hi ? B10 : B00;
        sb.w[3] = hi ? B11 : B01;
        __builtin_amdgcn_s_setprio(1);
        #pragma unroll
        for (int nb = 0; nb < 6; ++nb) {
            bfrag wa = *(const bfrag*)&OW[(nb * 16 + lr) * 96 + kb * 32 + lg * 8];
            yac[nb] = MFMA(wa, sb.v, yac[nb]);
        }
        __builtin_amdgcn_s_setprio(0);
    }

    // store: lane holds y[o = nb*16+lg*4+r][t = lr-token]; 16 lr = 64B contiguous
    if (t < MMTOK) {
        int flat = w * MMTOK + t;
        int ho = flat / HWD, wo = flat - ho * HWD;
        float* op = out + (size_t)b * CH * PLANE + (size_t)ho * HWD + wo;
        #pragma unroll
        for (int nb = 0; nb < 6; ++nb)
            #pragma unroll
            for (int r = 0; r < 4; ++r)
                op[(size_t)(nb * 16 + lg * 4 + r) * PLANE] = yac[nb][r];
    }
}

extern "C" void kernel_launch(void* const* d_in, const int* in_sizes, int n_in,
                              void* d_out, int out_size, void* d_ws, size_t ws_size,
                              hipStream_t stream) {
    const float* x  = (const float*)d_in[0];
    const float* qw = (const float*)d_in[1];
    const float* qb = (const float*)d_in[2];
    const float* bt = (const float*)d_in[3];
    const float* ow = (const float*)d_in[4];
    const float* ob = (const float*)d_in[5];
    float* out      = (float*)d_out;
    __hip_bfloat16* ws = (__hip_bfloat16*)d_ws;

    cvt_weights<<<(WS_TOT + 255) / 256, 256, 0, stream>>>(qw, ow, ws);

    int B = in_sizes[0] / (CH * HWD * HWD);      // 16
    int nblocks = B * 1024;                      // one block per window (16384, %8==0)
    wmsa_mfma<<<nblocks, 256, 0, stream>>>(x, ws, qb, bt, ob, out);
}

// Round 13
// 560.728 us; speedup vs baseline: 2.0585x; 2.0585x over previous
//
#include <hip/hip_runtime.h>
#include <hip/hip_bf16.h>

// WMSA round 9: single QKV GEMM phase + barrier-free 3-head attention.
//  - Q (all heads) -> s_win reuse; K -> s_k; V^T -> s_vT  (one C-store phase)
//  - swapped QK^T, in-lane softmax, wave-private P strip, O -> wave-private rows
//  - 4 barriers/block total; store convergence barrier restores write combining
//  - x-load: r9 pattern (uniform plane/instruction); store: r8 form (WRITE==ideal)
// One block (256 thr = 4 waves) per window; wave wv owns tokens [16wv,16wv+16).

#define CH    96
#define MMTOK 49
#define HWD   224
#define PLANE (HWD * HWD)

typedef __attribute__((ext_vector_type(8))) __bf16 bfrag;
typedef __attribute__((ext_vector_type(4))) float  f4;
#define MFMA(a,b,c) __builtin_amdgcn_mfma_f32_16x16x32_bf16(a,b,c,0,0,0)

// ws layout (bf16 element offsets): qkv_w [288][96], out_w [96][96]
#define WS_OW  27648
#define WS_TOT 36864

// LDS pitches (bf16 elems); row strides 16B multiples, <=2-way on b128 reads
#define PW_W 104   // s_win (x, then Q, then O-stack) and s_k
#define PW_V 72    // s_vT [96][64+8]
#define PW_P 72    // per-wave P strip [16][64+8]

extern "C" __global__ void __launch_bounds__(256)
cvt_weights(const float* __restrict__ qw, const float* __restrict__ ow,
            __hip_bfloat16* __restrict__ ws)
{
    int i = blockIdx.x * 256 + threadIdx.x;
    if (i >= WS_TOT) return;
    ws[i] = __float2bfloat16(i < WS_OW ? qw[i] : ow[i - WS_OW]);
}

extern "C" __global__ void __launch_bounds__(256, 3)
wmsa_mfma(const float* __restrict__ x,
          const __hip_bfloat16* __restrict__ ws,
          const float* __restrict__ qkvb,   // f32 [288]
          const float* __restrict__ bt,     // f32 [507]
          const float* __restrict__ outb,   // f32 [96]
          float* __restrict__ out)
{
    __shared__ __align__(16) __hip_bfloat16 s_win[64 * PW_W];   // x -> Q -> O-stack
    __shared__ __align__(16) __hip_bfloat16 s_k  [64 * PW_W];   // K [tok][h*32+d]
    __shared__ __align__(16) __hip_bfloat16 s_vT [96 * PW_V];   // V^T [h*32+d][tok]
    __shared__ __align__(16) __hip_bfloat16 s_P  [4][16 * PW_P];// per-wave P strip
    __shared__ float s_bias[507];

    const int tid  = threadIdx.x;
    // XCD-bijective swizzle (gridDim.x = 16384, %8==0)
    const int cpx  = gridDim.x >> 3;
    const int wid  = (blockIdx.x & 7) * cpx + (blockIdx.x >> 3);
    const int b    = wid >> 10;
    const int w    = wid & 1023;
    const int h0   = (w >> 5) * 7;
    const int w0   = (w & 31) * 7;
    const int lane = tid & 63;
    const int wv   = tid >> 6;
    const int lr   = lane & 15;
    const int lg   = lane >> 4;
    const int trow = wv * 16 + lg * 4;      // C-tile row base (global token)

    const __hip_bfloat16* QW = ws;
    const __hip_bfloat16* OW = ws + WS_OW;

    // ---- stage bias table ----
    for (int i = tid; i < 507; i += 256) s_bias[i] = bt[i];

    // ---- window load (r9 pattern): t = lane, c = wv + 4k, uniform plane per
    //      instruction, 24 batched loads, one drain ----
    {
        const int t  = lane;
        const int tt = (t < MMTOK) ? t : 0;
        const int ti = tt / 7, tj = tt - ti * 7;
        const float* xp = x + ((size_t)(b * CH + wv) * PLANE)
                            + (size_t)(h0 + ti) * HWD + (w0 + tj);
        float rx[24];
        #pragma unroll
        for (int k = 0; k < 24; ++k)
            rx[k] = xp[(size_t)k * 4 * PLANE];        // c = wv + 4k
        const float zm = (t < MMTOK) ? 1.f : 0.f;
        #pragma unroll
        for (int k = 0; k < 24; ++k)
            s_win[t * PW_W + wv + 4 * k] = __float2bfloat16(rx[k] * zm);
    }
    __syncthreads();                                   // [1] x staged

    // A-fragments (rows wv*16+lr, K=96 = 3 kblocks)
    bfrag aq[3];
    #pragma unroll
    for (int k = 0; k < 3; ++k)
        aq[k] = *(const bfrag*)&s_win[(wv * 16 + lr) * PW_W + k * 32 + lg * 8];
    __syncthreads();                                   // [2] aq hoisted everywhere

    // ---- per-lane bias indices: p = wv*16+lr fixed; k = m*16+lg*4+r ----
    const int p   = wv * 16 + lr;
    const bool pok = (p < MMTOK);
    const int pp  = pok ? p : 48;
    const int a1p = ((pp / 7) * 13 + (pp % 7)) * 3 + 252;
    int bidx[16];
    #pragma unroll
    for (int m = 0; m < 4; ++m)
        #pragma unroll
        for (int r = 0; r < 4; ++r) {
            int kt = m * 16 + lg * 4 + r;
            int kc = (kt < MMTOK) ? kt : 48;
            bidx[m * 4 + r] = a1p - ((kc / 7) * 13 + (kc % 7)) * 3;
        }

    const float inv_scale = 0.0180421959f;             // sqrt(3)/96

    // ==== QKV GEMM: all 288 cols in 3 groups, C-stores to LDS, no mid-barriers ====
    #pragma unroll
    for (int ob = 0; ob < 3; ++ob) {
        const __hip_bfloat16* QWrow = QW + (ob * 96 + lr) * 96 + lg * 8;
        f4 acc[6];
        #pragma unroll
        for (int n = 0; n < 6; ++n) {
            float bb = qkvb[ob * 96 + n * 16 + lr];
            acc[n] = f4{bb, bb, bb, bb};
        }
        bfrag b0[6], b1[6];
        #pragma unroll
        for (int n = 0; n < 6; ++n) b0[n] = *(const bfrag*)&QWrow[n * 16 * 96 + 0 * 32];
        #pragma unroll
        for (int n = 0; n < 6; ++n) b1[n] = *(const bfrag*)&QWrow[n * 16 * 96 + 1 * 32];
        __builtin_amdgcn_s_setprio(1);
        #pragma unroll
        for (int n = 0; n < 6; ++n) acc[n] = MFMA(aq[0], b0[n], acc[n]);
        __builtin_amdgcn_s_setprio(0);
        #pragma unroll
        for (int n = 0; n < 6; ++n) b0[n] = *(const bfrag*)&QWrow[n * 16 * 96 + 2 * 32];
        __builtin_amdgcn_s_setprio(1);
        #pragma unroll
        for (int n = 0; n < 6; ++n) acc[n] = MFMA(aq[1], b1[n], acc[n]);
        #pragma unroll
        for (int n = 0; n < 6; ++n) acc[n] = MFMA(aq[2], b0[n], acc[n]);
        __builtin_amdgcn_s_setprio(0);

        // C-store: n=0,1 -> Q (s_win cols ob*32..) ; n=2,3 -> K ; n=4,5 -> V^T
        #pragma unroll
        for (int n = 0; n < 6; ++n) {
            int part = n >> 1;
            int d = ((n & 1) << 4) + lr;
            #pragma unroll
            for (int r = 0; r < 4; ++r) {
                __hip_bfloat16 hv = __float2bfloat16(acc[n][r]);
                int tk = trow + r;
                if (part == 0)      s_win[tk * PW_W + ob * 32 + d] = hv;
                else if (part == 1) s_k[tk * PW_W + ob * 32 + d] = hv;
                else                s_vT[(ob * 32 + d) * PW_V + tk] = hv;
            }
        }
    }
    __syncthreads();                                   // [3] Q,K,V visible

    // ==== attention: 3 independent heads, ZERO barriers ====
    #pragma unroll
    for (int h = 0; h < 3; ++h) {
        // swapped QK^T: lane holds scores of its own query row p = wv*16+lr
        bfrag qf = *(const bfrag*)&s_win[(wv * 16 + lr) * PW_W + h * 32 + lg * 8];
        f4 sc[4];
        __builtin_amdgcn_s_setprio(1);
        #pragma unroll
        for (int m = 0; m < 4; ++m) {
            bfrag kf = *(const bfrag*)&s_k[(m * 16 + lr) * PW_W + h * 32 + lg * 8];
            f4 z = f4{0.f, 0.f, 0.f, 0.f};
            sc[m] = MFMA(kf, qf, z);
        }
        __builtin_amdgcn_s_setprio(0);

        // in-lane softmax (2 shuffles)
        float val[16];
        #pragma unroll
        for (int m = 0; m < 4; ++m)
            #pragma unroll
            for (int r = 0; r < 4; ++r)
                val[m * 4 + r] = fmaf(sc[m][r], inv_scale, s_bias[bidx[m * 4 + r] + h]);
        float mx = fmaxf(fmaxf(fmaxf(val[0], val[1]), fmaxf(val[2], val[3])),
                   fmaxf(fmaxf(fmaxf(val[4], val[5]), fmaxf(val[6], val[7])),
                   fmaxf(fmaxf(fmaxf(val[8], val[9]), fmaxf(val[10], val[11])),
                         fmaxf(fmaxf(val[12], val[13]), fmaxf(val[14], val[15])))));
        mx = fmaxf(mx, __shfl_xor(mx, 16));
        mx = fmaxf(mx, __shfl_xor(mx, 32));
        float sum = 0.f;
        #pragma unroll
        for (int m = 0; m < 4; ++m)
            #pragma unroll
            for (int r = 0; r < 4; ++r) {
                int i = m * 4 + r;
                float e = __expf(val[i] - mx);
                e = (m * 16 + lg * 4 + r < MMTOK) ? e : 0.f;
                val[i] = e;
                sum += e;
            }
        sum += __shfl_xor(sum, 16);
        sum += __shfl_xor(sum, 32);
        const float inv = pok ? (1.0f / sum) : 0.f;

        // P strip (wave-private), 4x uint2; same-wave ordering, no barrier
        #pragma unroll
        for (int m = 0; m < 4; ++m) {
            union { __hip_bfloat16 hh[4]; uint2 u; } pk;
            #pragma unroll
            for (int r = 0; r < 4; ++r) pk.hh[r] = __float2bfloat16(val[m * 4 + r] * inv);
            *(uint2*)&s_P[wv][lr * PW_P + m * 16 + lg * 4] = pk.u;
        }

        // PV: O strip [16 p][32 d] = P[16][64] x V[64][32]
        bfrag pa0 = *(const bfrag*)&s_P[wv][lr * PW_P + 0 * 32 + lg * 8];
        bfrag pa1 = *(const bfrag*)&s_P[wv][lr * PW_P + 1 * 32 + lg * 8];
        __builtin_amdgcn_s_setprio(1);
        #pragma unroll
        for (int n = 0; n < 2; ++n) {
            bfrag vb0 = *(const bfrag*)&s_vT[(h * 32 + n * 16 + lr) * PW_V + 0 * 32 + lg * 8];
            bfrag vb1 = *(const bfrag*)&s_vT[(h * 32 + n * 16 + lr) * PW_V + 1 * 32 + lg * 8];
            f4 oc = f4{0.f, 0.f, 0.f, 0.f};
            oc = MFMA(pa0, vb0, oc);
            oc = MFMA(pa1, vb1, oc);
            // O overwrites Q cols of head h (dead); wave-private rows
            #pragma unroll
            for (int r = 0; r < 4; ++r)
                s_win[(trow + r) * PW_W + h * 32 + n * 16 + lr] = __float2bfloat16(oc[r]);
        }
        __builtin_amdgcn_s_setprio(0);
    }

    // ==== out-proj (A = own rows of s_win; same-wave ordering, no barrier) ====
    bfrag sa[3];
    #pragma unroll
    for (int k = 0; k < 3; ++k)
        sa[k] = *(const bfrag*)&s_win[(wv * 16 + lr) * PW_W + k * 32 + lg * 8];
    f4 yac[6];
    #pragma unroll
    for (int n = 0; n < 6; ++n) {
        float bb = outb[n * 16 + lr];
        yac[n] = f4{bb, bb, bb, bb};
    }
    {
        const __hip_bfloat16* OWrow = OW + lr * 96 + lg * 8;
        bfrag c0[6], c1[6];
        #pragma unroll
        for (int n = 0; n < 6; ++n) c0[n] = *(const bfrag*)&OWrow[n * 16 * 96 + 0 * 32];
        #pragma unroll
        for (int n = 0; n < 6; ++n) c1[n] = *(const bfrag*)&OWrow[n * 16 * 96 + 1 * 32];
        __builtin_amdgcn_s_setprio(1);
        #pragma unroll
        for (int n = 0; n < 6; ++n) yac[n] = MFMA(sa[0], c0[n], yac[n]);
        __builtin_amdgcn_s_setprio(0);
        #pragma unroll
        for (int n = 0; n < 6; ++n) c0[n] = *(const bfrag*)&OWrow[n * 16 * 96 + 2 * 32];
        __builtin_amdgcn_s_setprio(1);
        #pragma unroll
        for (int n = 0; n < 6; ++n) yac[n] = MFMA(sa[1], c1[n], yac[n]);
        #pragma unroll
        for (int n = 0; n < 6; ++n) yac[n] = MFMA(sa[2], c0[n], yac[n]);
        __builtin_amdgcn_s_setprio(0);
    }

    __syncthreads();   // [4] converge waves: stores land together (write combining)

    // store (r8 form, confirmed WRITE == ideal): flat = w*49 + t
    #pragma unroll
    for (int n = 0; n < 6; ++n) {
        int o = n * 16 + lr;
        #pragma unroll
        for (int r = 0; r < 4; ++r) {
            int t = trow + r;
            if (t < MMTOK) {
                int flat = w * MMTOK + t;
                int ho = flat / HWD, wo = flat - ho * HWD;
                out[((b * CH + o) * HWD + ho) * HWD + wo] = yac[n][r];
            }
        }
    }
}

extern "C" void kernel_launch(void* const* d_in, const int* in_sizes, int n_in,
                              void* d_out, int out_size, void* d_ws, size_t ws_size,
                              hipStream_t stream) {
    const float* x  = (const float*)d_in[0];
    const float* qw = (const float*)d_in[1];
    const float* qb = (const float*)d_in[2];
    const float* bt = (const float*)d_in[3];
    const float* ow = (const float*)d_in[4];
    const float* ob = (const float*)d_in[5];
    float* out      = (float*)d_out;
    __hip_bfloat16* ws = (__hip_bfloat16*)d_ws;

    cvt_weights<<<(WS_TOT + 255) / 256, 256, 0, stream>>>(qw, ow, ws);

    int B = in_sizes[0] / (CH * HWD * HWD);      // 16
    int nblocks = B * 1024;                      // one block per window (16384, %8==0)
    wmsa_mfma<<<nblocks, 256, 0, stream>>>(x, ws, qb, bt, ob, out);
}